// Round 5
// baseline (3342.429 us; speedup 1.0000x reference)
//
#include <hip/hip_runtime.h>

// ---------------------------------------------------------------------------
// DendriticMLP on MI355X — round 8.
// Round-7 post-mortem: SGB phase pipeline REGRESSED (420->513): the aH[2]
// ping-pong created WAR hazards (ds_read into a reg still being consumed by
// in-flight MFMAs stalls in-order issue of the following MFMA cluster).
// Revised model of the r4/r6 step (7875 cyc): ~1150 read-gate (8-wave LDS
// burst contention) + 4656 MFMA-issue-bound + ~800 stage/drain tail.
// Gate+tail are per-step CONSTANTS -> amortize: BK=64 super-steps,
// single-buffered (2x width in same LDS), 2-barrier stage/compute split
// (round-4's proven structure). Everything else = round 6 exactly
// (f16-plane layout, swz, fused gating, persistent ctx planes).
//  - dend: 256x320 tile, waves 2x4 (wave 128x80), 16 super-steps, 144 KB
//  - gemm: (64*TMW)x128 tile, waves 4x2, TMW=4 (96 KB) / TMW=2 out-layer
//    (64 KB, grid 32x8 = 256 blocks -> full CU coverage)
// ---------------------------------------------------------------------------

#define AS1 __attribute__((address_space(1)))
#define AS3 __attribute__((address_space(3)))

typedef _Float16 f16x8 __attribute__((ext_vector_type(8)));
typedef _Float16 f16x4 __attribute__((ext_vector_type(4)));
typedef float    f32x4 __attribute__((ext_vector_type(4)));

// swizzled halfword offset of logical chunk q (0..3) in row of a [rows][32]
// f16 tile: physical chunk = q ^ ((row>>1)&3) -> frag reads 2-way max (free).
__device__ __forceinline__ int swz(int row, int q) {
    return row * 32 + ((q ^ ((row >> 1) & 3)) << 3);
}

// ---------------------------------------------------------------------------
// split: fp32 -> f16 hi + f16 lo planes (a ~= hi+lo, err ~2^-22 |a|)
// ---------------------------------------------------------------------------
__global__ __launch_bounds__(256) void split_kernel(const float* __restrict__ s,
                                                    _Float16* __restrict__ hi,
                                                    _Float16* __restrict__ lo, int n4) {
    int i = blockIdx.x * 256 + threadIdx.x;
    if (i >= n4) return;
    float4 a = ((const float4*)s)[i];
    f16x4 h, l;
    h.x = (_Float16)a.x; l.x = (_Float16)(a.x - (float)h.x);
    h.y = (_Float16)a.y; l.y = (_Float16)(a.y - (float)h.y);
    h.z = (_Float16)a.z; l.z = (_Float16)(a.z - (float)h.z);
    h.w = (_Float16)a.w; l.w = (_Float16)(a.w - (float)h.w);
    ((f16x4*)hi)[i] = h;
    ((f16x4*)lo)[i] = l;
}

// DMA a [ROWS][32] f16 plane tile into swizzled LDS (512-thread blocks).
// Global source per-lane permuted; LDS dest wave-uniform base + lane*16.
template <int ROWS>
__device__ __forceinline__ void dma_plane(const _Float16* __restrict__ g, long row0,
                                          int ldHalf, int kcol, _Float16* lds, int tid) {
#pragma unroll
    for (int rep = 0; rep < ROWS / 128; ++rep) {
        const int s = tid + rep * 512;           // physical 16B slot, ROWS*4 total
        const int row = s >> 2, cp = s & 3;
        const int src = cp ^ ((row >> 1) & 3);   // logical chunk at this slot
        const _Float16* gp = g + (row0 + row) * (long)ldHalf + kcol + src * 8;
        __builtin_amdgcn_global_load_lds((const AS1 void*)gp,
                                         (AS3 void*)(lds + ((s & ~63) << 3)), 16, 0, 0);
    }
}

// ---------------------------------------------------------------------------
// Split GEMM: C[M,N] = (A[M,K] @ B[N,K]^T + bias[N]) * gates[M,N]?; A as f16
// hi/lo planes (DMA), B fp32 (reg-prefetch, split once into LDS planes).
// (64*TMW)x128 tile, 8 waves 4x2 (wave (16*TMW)x64), BK=64 single-buffer,
// 2-barrier stage/compute per super-step.
// ---------------------------------------------------------------------------
template <int TMW>
__global__ __launch_bounds__(512, 2) void gemm_f16p(
    const _Float16* __restrict__ AH, const _Float16* __restrict__ AL,
    const float* __restrict__ B, const float* __restrict__ bias,
    const float* __restrict__ gates, float* __restrict__ C, int N, int K) {
    constexpr int MROWS = 64 * TMW;              // block M-tile
    constexpr int ATILE = MROWS * 32;            // halfwords per 32-col tile
    constexpr int BTILE = 128 * 32;
    extern __shared__ __align__(16) char smem[];
    _Float16* sAh = (_Float16*)smem;             // [2 tiles][MROWS][32]
    _Float16* sAl = sAh + 2 * ATILE;
    _Float16* sBh = sAh + 4 * ATILE;             // [2 tiles][128][32]
    _Float16* sBl = sBh + 2 * BTILE;
    const int tid = threadIdx.x;
    const int w = tid >> 6, lane = tid & 63;
    const int wm = w >> 1, wn = w & 1;           // 4 x 2 waves
    const int q = lane >> 4, l15 = lane & 15;
    const int bm = blockIdx.x, bn = blockIdx.y;
    const long brow0 = (long)bn * 128;
    const long arow0 = (long)bm * MROWS;
    f32x4 acc[TMW][4] = {};
    float4 pre[4];
    auto loadB = [&](int ss) {                   // 128 rows x 64 cols fp32
#pragma unroll
        for (int j = 0; j < 4; ++j) {
            const int c = tid + j * 512;         // 2048 float4 chunks
            const int row = c >> 4, hc = c & 15;
            pre[j] = *(const float4*)(B + (brow0 + row) * (long)K + ss * 64 + (hc << 2));
        }
    };
    auto writeB = [&]() {
#pragma unroll
        for (int j = 0; j < 4; ++j) {
            const int c = tid + j * 512;
            const int row = c >> 4, hc = c & 15;
            const int kk = hc >> 3, h7 = hc & 7;
            const float4 v = pre[j];
            f16x4 h, l;
            h.x = (_Float16)v.x; l.x = (_Float16)(v.x - (float)h.x);
            h.y = (_Float16)v.y; l.y = (_Float16)(v.y - (float)h.y);
            h.z = (_Float16)v.z; l.z = (_Float16)(v.z - (float)h.z);
            h.w = (_Float16)v.w; l.w = (_Float16)(v.w - (float)h.w);
            const int off = kk * BTILE + row * 32 +
                            (((h7 >> 1) ^ ((row >> 1) & 3)) << 3) + ((h7 & 1) << 2);
            *(f16x4*)(sBh + off) = h;
            *(f16x4*)(sBl + off) = l;
        }
    };
    auto stageA = [&](int ss) {
#pragma unroll
        for (int kk = 0; kk < 2; ++kk) {
            dma_plane<MROWS>(AH, arow0, K, ss * 64 + kk * 32, sAh + kk * ATILE, tid);
            dma_plane<MROWS>(AL, arow0, K, ss * 64 + kk * 32, sAl + kk * ATILE, tid);
        }
    };
    loadB(0);
    stageA(0);
    writeB();
    __syncthreads();
    const int NS = K >> 6;
    for (int ss = 0; ss < NS; ++ss) {
        if (ss + 1 < NS) loadB(ss + 1);          // reg prefetch, hides under MFMA
#pragma unroll
        for (int kk = 0; kk < 2; ++kk) {
            f16x8 bH[4], bL[4];
#pragma unroll
            for (int tn = 0; tn < 4; ++tn) {
                const int rowb = wn * 64 + tn * 16 + l15;
                bH[tn] = *(const f16x8*)&sBh[kk * BTILE + swz(rowb, q)];
                bL[tn] = *(const f16x8*)&sBl[kk * BTILE + swz(rowb, q)];
            }
            __builtin_amdgcn_s_setprio(1);
#pragma unroll
            for (int tm = 0; tm < TMW; ++tm) {
                const int row = wm * (16 * TMW) + tm * 16 + l15;
                const f16x8 aH = *(const f16x8*)&sAh[kk * ATILE + swz(row, q)];
                const f16x8 aL = *(const f16x8*)&sAl[kk * ATILE + swz(row, q)];
#pragma unroll
                for (int tn = 0; tn < 4; ++tn) {
                    acc[tm][tn] = __builtin_amdgcn_mfma_f32_16x16x32_f16(aH, bH[tn], acc[tm][tn], 0, 0, 0);
                    acc[tm][tn] = __builtin_amdgcn_mfma_f32_16x16x32_f16(aH, bL[tn], acc[tm][tn], 0, 0, 0);
                    acc[tm][tn] = __builtin_amdgcn_mfma_f32_16x16x32_f16(aL, bH[tn], acc[tm][tn], 0, 0, 0);
                }
            }
            __builtin_amdgcn_s_setprio(0);
        }
        __syncthreads();                         // compute reads done
        if (ss + 1 < NS) {
            stageA(ss + 1);                      // DMA into (now free) buffer
            writeB();                            // split once, amortized
        }
        __syncthreads();                         // drains DMA + ds_writes
    }
    float bv[4];
#pragma unroll
    for (int tn = 0; tn < 4; ++tn) bv[tn] = bias[bn * 128 + wn * 64 + tn * 16 + l15];
#pragma unroll
    for (int tm = 0; tm < TMW; ++tm) {
        const int m0 = bm * MROWS + wm * (16 * TMW) + tm * 16 + q * 4;
#pragma unroll
        for (int tn = 0; tn < 4; ++tn) {
            const int n = bn * 128 + wn * 64 + tn * 16 + l15;
#pragma unroll
            for (int r = 0; r < 4; ++r) {
                float o = acc[tm][tn][r] + bv[tn];
                if (gates) o *= gates[(long)(m0 + r) * N + n];  // fused gating
                C[(long)(m0 + r) * N + n] = o;
            }
        }
    }
}

// ---------------------------------------------------------------------------
// Dendrite GEMM + abs-max gating epilogue. dend[b,n] = ctx[b,:].seg[n,:],
// n = h*10+s, 20480 rows. Tile 256(b)x320(n) = 32 h-groups, 8 waves 2x4
// (wave 128x80 = 8x5). BK=64 single-buffer, 2-barrier super-steps, 144 KB.
// Epilogue: acc -> LDS [64][320] x4 chunks, argmax_s |dend| (strict > =
// jnp.argmax), sigmoid.
// ---------------------------------------------------------------------------
__global__ __launch_bounds__(512, 2) void dend_gemm(const _Float16* __restrict__ AH,
                                                    const _Float16* __restrict__ AL,
                                                    const float* __restrict__ seg,
                                                    float* __restrict__ gates) {
    constexpr int ATILE = 256 * 32;              // halfwords per 32-col tile
    constexpr int BTILE = 320 * 32;
    extern __shared__ __align__(16) char smem[];
    _Float16* sAh = (_Float16*)smem;             // [2][256][32] = 32 KB
    _Float16* sAl = sAh + 2 * ATILE;             // 32 KB
    _Float16* sBh = sAh + 4 * ATILE;             // [2][320][32] = 40 KB
    _Float16* sBl = sBh + 2 * BTILE;             // 40 KB -> total 144 KB
    float* Cred = (float*)smem;                  // [64][320] union, 80 KB
    const int tid = threadIdx.x;
    const int w = tid >> 6, lane = tid & 63;
    const int wm = w >> 2, wn = w & 3;           // 2 x 4 waves
    const int q = lane >> 4, l15 = lane & 15;
    const int bm = blockIdx.x, bn = blockIdx.y;
    const long brow0 = (long)bn * 320;
    const long arow0 = (long)bm * 256;
    f32x4 acc[8][5] = {};
    float4 pre[10];
    auto loadB = [&](int ss) {                   // 320 rows x 64 cols fp32
#pragma unroll
        for (int j = 0; j < 10; ++j) {
            const int c = tid + j * 512;         // 5120 float4 chunks
            const int row = c >> 4, hc = c & 15;
            pre[j] = *(const float4*)(seg + (brow0 + row) * 1024L + ss * 64 + (hc << 2));
        }
    };
    auto writeB = [&]() {
#pragma unroll
        for (int j = 0; j < 10; ++j) {
            const int c = tid + j * 512;
            const int row = c >> 4, hc = c & 15;
            const int kk = hc >> 3, h7 = hc & 7;
            const float4 v = pre[j];
            f16x4 h, l;
            h.x = (_Float16)v.x; l.x = (_Float16)(v.x - (float)h.x);
            h.y = (_Float16)v.y; l.y = (_Float16)(v.y - (float)h.y);
            h.z = (_Float16)v.z; l.z = (_Float16)(v.z - (float)h.z);
            h.w = (_Float16)v.w; l.w = (_Float16)(v.w - (float)h.w);
            const int off = kk * BTILE + row * 32 +
                            (((h7 >> 1) ^ ((row >> 1) & 3)) << 3) + ((h7 & 1) << 2);
            *(f16x4*)(sBh + off) = h;
            *(f16x4*)(sBl + off) = l;
        }
    };
    auto stageA = [&](int ss) {
#pragma unroll
        for (int kk = 0; kk < 2; ++kk) {
            dma_plane<256>(AH, arow0, 1024, ss * 64 + kk * 32, sAh + kk * ATILE, tid);
            dma_plane<256>(AL, arow0, 1024, ss * 64 + kk * 32, sAl + kk * ATILE, tid);
        }
    };
    loadB(0);
    stageA(0);
    writeB();
    __syncthreads();
    for (int ss = 0; ss < 16; ++ss) {
        if (ss < 15) loadB(ss + 1);              // reg prefetch, hides under MFMA
#pragma unroll
        for (int kk = 0; kk < 2; ++kk) {
            f16x8 bH[5], bL[5];
#pragma unroll
            for (int tn = 0; tn < 5; ++tn) {
                const int rowb = wn * 80 + tn * 16 + l15;
                bH[tn] = *(const f16x8*)&sBh[kk * BTILE + swz(rowb, q)];
                bL[tn] = *(const f16x8*)&sBl[kk * BTILE + swz(rowb, q)];
            }
            __builtin_amdgcn_s_setprio(1);
#pragma unroll
            for (int tm = 0; tm < 8; ++tm) {
                const int row = wm * 128 + tm * 16 + l15;
                const f16x8 aH = *(const f16x8*)&sAh[kk * ATILE + swz(row, q)];
                const f16x8 aL = *(const f16x8*)&sAl[kk * ATILE + swz(row, q)];
#pragma unroll
                for (int tn = 0; tn < 5; ++tn) {
                    acc[tm][tn] = __builtin_amdgcn_mfma_f32_16x16x32_f16(aH, bH[tn], acc[tm][tn], 0, 0, 0);
                    acc[tm][tn] = __builtin_amdgcn_mfma_f32_16x16x32_f16(aH, bL[tn], acc[tm][tn], 0, 0, 0);
                    acc[tm][tn] = __builtin_amdgcn_mfma_f32_16x16x32_f16(aL, bH[tn], acc[tm][tn], 0, 0, 0);
                }
            }
            __builtin_amdgcn_s_setprio(0);
        }
        __syncthreads();                         // compute reads done
        if (ss < 15) {
            stageA(ss + 1);                      // DMA into (now free) buffer
            writeB();
        }
        __syncthreads();                         // drains DMA + ds_writes
    }
    // epilogue: four 64-row chunks through LDS [64][320]. Scan reads stride
    // 10 fp32 -> <=4-way aliasing, epilogue-only (negligible).
    // chunk c rows = bm*256 + c*64..+63 -> wave wm == c>>1, tm (c&1)*4..+3
    for (int c = 0; c < 4; ++c) {
        __syncthreads();
        if (wm == (c >> 1)) {
            const int tmb = (c & 1) * 4;
#pragma unroll
            for (int tt = 0; tt < 4; ++tt)
#pragma unroll
                for (int tn = 0; tn < 5; ++tn)
#pragma unroll
                    for (int r = 0; r < 4; ++r)
                        Cred[(tt * 16 + q * 4 + r) * 320 + wn * 80 + tn * 16 + l15] =
                            acc[tmb + tt][tn][r];
        }
        __syncthreads();
        for (int p = tid; p < 2048; p += 512) {
            const int bb = p >> 5, hh = p & 31;
            const float* d = &Cred[bb * 320 + hh * 10];
            float best = d[0], ba = fabsf(d[0]);
#pragma unroll
            for (int s = 1; s < 10; ++s) {
                const float v = d[s], a = fabsf(v);
                if (a > ba) { ba = a; best = v; }    // strict >: first occurrence
            }
            const float gate = 1.f / (1.f + expf(-best));
            const int bg = bm * 256 + c * 64 + bb;
            const int h = bn * 32 + hh;
            gates[(long)bg * 2048 + h] = gate;
        }
    }
}

// ---------------------------------------------------------------------------
// KWinners on pre-gated v: exact 102nd-largest via radix select on
// order-preserving uint keys; keep where key >= kth (jnp `x >= kth` ties);
// emit h as f16 hi/lo planes (feeds next GEMM's A-DMA path).
// ---------------------------------------------------------------------------
__global__ __launch_bounds__(256) void kwinners_kernel(const float* __restrict__ vin,
                                                       _Float16* __restrict__ hH,
                                                       _Float16* __restrict__ hL) {
    __shared__ unsigned hist[256];
    __shared__ unsigned scan[257];
    __shared__ int sb, srank;
    const int tid = threadIdx.x;
    const long base = (long)blockIdx.x * 2048;
    float v[8];
    unsigned u[8];
#pragma unroll
    for (int j = 0; j < 8; ++j) {
        const int i = j * 256 + tid;
        const float val = vin[base + i];
        v[j] = val;
        const unsigned b = __float_as_uint(val);
        u[j] = b ^ (unsigned)((((int)b) >> 31) | 0x80000000);  // monotone map
    }
    unsigned prefix = 0, pmask = 0;
    int rank = 102;
    for (int round = 0; round < 4; ++round) {
        const int shift = 24 - (round << 3);
        hist[tid] = 0;
        if (tid == 0) scan[256] = 0;
        __syncthreads();
#pragma unroll
        for (int j = 0; j < 8; ++j)
            if ((u[j] & pmask) == prefix) atomicAdd(&hist[(u[j] >> shift) & 255], 1u);
        __syncthreads();
        scan[tid] = hist[tid];
        __syncthreads();
        for (int off = 1; off < 256; off <<= 1) {  // inclusive suffix sum
            const unsigned t = scan[tid] + ((tid + off < 256) ? scan[tid + off] : 0u);
            __syncthreads();
            scan[tid] = t;
            __syncthreads();
        }
        if (scan[tid] >= (unsigned)rank && scan[tid + 1] < (unsigned)rank) {
            sb = tid;
            srank = rank - (int)scan[tid + 1];
        }
        __syncthreads();
        prefix |= ((unsigned)sb) << shift;
        pmask |= 255u << shift;
        rank = srank;
        __syncthreads();
    }
#pragma unroll
    for (int j = 0; j < 8; ++j) {
        const int i = j * 256 + tid;
        const float hv = (u[j] >= prefix) ? v[j] : 0.f;
        const _Float16 hi = (_Float16)hv;
        hH[base + i] = hi;
        hL[base + i] = (_Float16)(hv - (float)hi);
    }
}

// ---------------------------------------------------------------------------
extern "C" void kernel_launch(void* const* d_in, const int* in_sizes, int n_in,
                              void* d_out, int out_size, void* d_ws, size_t ws_size,
                              hipStream_t stream) {
    const float* x    = (const float*)d_in[0];
    const float* ctx  = (const float*)d_in[1];
    const float* w1   = (const float*)d_in[2];
    const float* b1   = (const float*)d_in[3];
    const float* seg1 = (const float*)d_in[4];
    const float* w2   = (const float*)d_in[5];
    const float* b2   = (const float*)d_in[6];
    const float* seg2 = (const float*)d_in[7];
    const float* wo   = (const float*)d_in[8];
    const float* bo   = (const float*)d_in[9];

    // 96 MB workspace, time-multiplexed (gate fused into gemm frees 32 MB):
    //  [0,32):  gates1 -> h planes (hH@0, hL@16) after gates1 dead
    //  [32,64): v1 -> gates2 after v1 dead
    //  [64,96): ctxH@64 ctxL@72 xH@80 xL@88 -> v2 after ctx/x dead
    char* base = (char*)d_ws;
    float*    gates1 = (float*)base;
    _Float16* hH     = (_Float16*)base;
    _Float16* hL     = (_Float16*)(base + (16L << 20));
    float*    v1     = (float*)(base + (32L << 20));
    float*    gates2 = (float*)(base + (32L << 20));
    _Float16* ctxH   = (_Float16*)(base + (64L << 20));
    _Float16* ctxL   = (_Float16*)(base + (72L << 20));
    _Float16* xH     = (_Float16*)(base + (80L << 20));
    _Float16* xL     = (_Float16*)(base + (88L << 20));
    float*    v2     = (float*)(base + (64L << 20));
    (void)ws_size;

    hipFuncSetAttribute((const void*)dend_gemm,
                        hipFuncAttributeMaxDynamicSharedMemorySize, 147456);
    hipFuncSetAttribute((const void*)&gemm_f16p<4>,
                        hipFuncAttributeMaxDynamicSharedMemorySize, 98304);
    hipFuncSetAttribute((const void*)&gemm_f16p<2>,
                        hipFuncAttributeMaxDynamicSharedMemorySize, 65536);

    const int n4_ctx = (4096 * 1024) / 4;  // 1M float4 -> 4096 blocks

    // layer 1
    split_kernel<<<dim3(4096), dim3(256), 0, stream>>>(ctx, ctxH, ctxL, n4_ctx);
    split_kernel<<<dim3(4096), dim3(256), 0, stream>>>(x, xH, xL, n4_ctx);
    dend_gemm<<<dim3(16, 64), dim3(512), 147456, stream>>>(ctxH, ctxL, seg1, gates1);
    gemm_f16p<4><<<dim3(16, 16), dim3(512), 98304, stream>>>(xH, xL, w1, b1, gates1,
                                                             v1, 2048, 1024);
    kwinners_kernel<<<dim3(4096), dim3(256), 0, stream>>>(v1, hH, hL);
    // layer 2 (ctx planes persist — no re-split needed)
    dend_gemm<<<dim3(16, 64), dim3(512), 147456, stream>>>(ctxH, ctxL, seg2, gates2);
    gemm_f16p<4><<<dim3(16, 16), dim3(512), 98304, stream>>>(hH, hL, w2, b2, gates2,
                                                             v2, 2048, 2048);
    kwinners_kernel<<<dim3(4096), dim3(256), 0, stream>>>(v2, hH, hL);
    // output layer (no gating); 128-row tile -> 256 blocks, full CU coverage
    gemm_f16p<2><<<dim3(32, 8), dim3(512), 65536, stream>>>(hH, hL, wo, bo, nullptr,
                                                            (float*)d_out, 1024, 2048);
}

// Round 6
// 1215.848 us; speedup vs baseline: 2.7491x; 2.7491x over previous
//
#include <hip/hip_runtime.h>

// ---------------------------------------------------------------------------
// DendriticMLP on MI355X — round 9 (consolidation).
// r8 post-mortem: BK=64 spilled pre[10] to scratch (WRITE_SIZE 35KB->930MB,
// hbm_bytes 2.67GB = 512thr x 160B x 2 x 16steps x 1024blocks). Hypothesis
// never tested. r5/r7/r8 all regressed vs r6 (1250us) for distinct reasons
// (fp32 bank geometry / WAR ping-pong hazards / reg spill); r4 and r6 hit the
// SAME per-CU throughput at different occupancy -> dend ~420us is structural
// for this decomposition. This round = r6 verbatim + the one clean win:
// output-layer GEMM ran 128 blocks on 256 CUs (half idle, ~100us). Template
// the M-tile: TMW=2 -> 128-row tile, grid (32,8)=256 blocks, 64KB LDS.
// Everything else byte-identical to r6.
// ---------------------------------------------------------------------------

#define AS1 __attribute__((address_space(1)))
#define AS3 __attribute__((address_space(3)))

typedef _Float16 f16x8 __attribute__((ext_vector_type(8)));
typedef _Float16 f16x4 __attribute__((ext_vector_type(4)));
typedef float    f32x4 __attribute__((ext_vector_type(4)));

// swizzled halfword offset of logical chunk q (0..3) in row of a [rows][32]
// f16 tile: physical chunk = q ^ ((row>>1)&3) -> frag reads 2-way max (free).
__device__ __forceinline__ int swz(int row, int q) {
    return row * 32 + ((q ^ ((row >> 1) & 3)) << 3);
}

// ---------------------------------------------------------------------------
// split: fp32 -> f16 hi + f16 lo planes (a ~= hi+lo, err ~2^-22 |a|)
// ---------------------------------------------------------------------------
__global__ __launch_bounds__(256) void split_kernel(const float* __restrict__ s,
                                                    _Float16* __restrict__ hi,
                                                    _Float16* __restrict__ lo, int n4) {
    int i = blockIdx.x * 256 + threadIdx.x;
    if (i >= n4) return;
    float4 a = ((const float4*)s)[i];
    f16x4 h, l;
    h.x = (_Float16)a.x; l.x = (_Float16)(a.x - (float)h.x);
    h.y = (_Float16)a.y; l.y = (_Float16)(a.y - (float)h.y);
    h.z = (_Float16)a.z; l.z = (_Float16)(a.z - (float)h.z);
    h.w = (_Float16)a.w; l.w = (_Float16)(a.w - (float)h.w);
    ((f16x4*)hi)[i] = h;
    ((f16x4*)lo)[i] = l;
}

// DMA a [ROWS][32] f16 plane tile into swizzled LDS (512-thread blocks).
// Global source per-lane permuted; LDS dest wave-uniform base + lane*16.
template <int ROWS>
__device__ __forceinline__ void dma_plane(const _Float16* __restrict__ g, long row0,
                                          int ldHalf, int kcol, _Float16* lds, int tid) {
#pragma unroll
    for (int rep = 0; rep < ROWS / 128; ++rep) {
        const int s = tid + rep * 512;           // physical 16B slot, ROWS*4 total
        const int row = s >> 2, cp = s & 3;
        const int src = cp ^ ((row >> 1) & 3);   // logical chunk at this slot
        const _Float16* gp = g + (row0 + row) * (long)ldHalf + kcol + src * 8;
        __builtin_amdgcn_global_load_lds((const AS1 void*)gp,
                                         (AS3 void*)(lds + ((s & ~63) << 3)), 16, 0, 0);
    }
}

// ---------------------------------------------------------------------------
// Split GEMM: C[M,N] = (A[M,K] @ B[N,K]^T + bias[N]) * gates[M,N]?; A as f16
// hi/lo planes (DMA), B fp32 (reg-prefetch, split once into LDS planes).
// (64*TMW)x128 tile, 8 waves 4x2 (wave (16*TMW)x64), BK=32 double-buffered,
// single-barrier pipeline (round-6 structure).
// ---------------------------------------------------------------------------
template <int TMW>
__global__ __launch_bounds__(512, 2) void gemm_f16p(
    const _Float16* __restrict__ AH, const _Float16* __restrict__ AL,
    const float* __restrict__ B, const float* __restrict__ bias,
    const float* __restrict__ gates, float* __restrict__ C, int N, int K) {
    constexpr int MROWS = 64 * TMW;              // block M-tile
    constexpr int ATILE = MROWS * 32;            // halfwords per plane buffer
    constexpr int BTILE = 128 * 32;
    extern __shared__ __align__(16) char smem[];
    _Float16* sAh0 = (_Float16*)smem;
    _Float16* sAl0 = sAh0 + ATILE;
    _Float16* sAh1 = sAh0 + 2 * ATILE;
    _Float16* sAl1 = sAh0 + 3 * ATILE;
    _Float16* sBh0 = sAh0 + 4 * ATILE;
    _Float16* sBl0 = sBh0 + BTILE;
    _Float16* sBh1 = sBh0 + 2 * BTILE;
    _Float16* sBl1 = sBh0 + 3 * BTILE;           // TMW=4: 96 KB, TMW=2: 64 KB
    const int tid = threadIdx.x;
    const int w = tid >> 6, lane = tid & 63;
    const int wm = w >> 1, wn = w & 1;           // 4 x 2 waves
    const int q = lane >> 4, l15 = lane & 15;
    const int bm = blockIdx.x, bn = blockIdx.y;
    const long brow0 = (long)bn * 128;
    f32x4 acc[TMW][4] = {};
    float4 pre[2];
    auto loadB = [&](int kt) {
#pragma unroll
        for (int j = 0; j < 2; ++j) {
            const int c = tid + j * 512;             // 1024 float4 chunks
            const int row = c >> 3, hc = c & 7;
            pre[j] = *(const float4*)(B + (brow0 + row) * (long)K + (kt << 5) + (hc << 2));
        }
    };
    auto writeB = [&](_Float16* bh, _Float16* bl) {
#pragma unroll
        for (int j = 0; j < 2; ++j) {
            const int c = tid + j * 512;
            const int row = c >> 3, hc = c & 7;
            const float4 v = pre[j];
            f16x4 h, l;
            h.x = (_Float16)v.x; l.x = (_Float16)(v.x - (float)h.x);
            h.y = (_Float16)v.y; l.y = (_Float16)(v.y - (float)h.y);
            h.z = (_Float16)v.z; l.z = (_Float16)(v.z - (float)h.z);
            h.w = (_Float16)v.w; l.w = (_Float16)(v.w - (float)h.w);
            const int off = row * 32 + (((hc >> 1) ^ ((row >> 1) & 3)) << 3) + ((hc & 1) << 2);
            *(f16x4*)(bh + off) = h;
            *(f16x4*)(bl + off) = l;
        }
    };
    loadB(0);
    dma_plane<MROWS>(AH, (long)bm * MROWS, K, 0, sAh0, tid);
    dma_plane<MROWS>(AL, (long)bm * MROWS, K, 0, sAl0, tid);
    writeB(sBh0, sBl0);
    __syncthreads();
    const int ksteps = K >> 5;
    for (int kt = 0; kt < ksteps; ++kt) {
        const bool odd = kt & 1;
        const _Float16 *cAh = odd ? sAh1 : sAh0, *cAl = odd ? sAl1 : sAl0;
        const _Float16 *cBh = odd ? sBh1 : sBh0, *cBl = odd ? sBl1 : sBl0;
        _Float16 *nAh = odd ? sAh0 : sAh1, *nAl = odd ? sAl0 : sAl1;
        _Float16 *nBh = odd ? sBh0 : sBh1, *nBl = odd ? sBl0 : sBl1;
        if (kt + 1 < ksteps) {                       // async; drained at barrier
            loadB(kt + 1);                           // regs (vmcnt)
            dma_plane<MROWS>(AH, (long)bm * MROWS, K, (kt + 1) << 5, nAh, tid);
            dma_plane<MROWS>(AL, (long)bm * MROWS, K, (kt + 1) << 5, nAl, tid);
        }
        f16x8 bH[4], bL[4];
#pragma unroll
        for (int tn = 0; tn < 4; ++tn) {
            const int rowb = wn * 64 + tn * 16 + l15;
            bH[tn] = *(const f16x8*)&cBh[swz(rowb, q)];
            bL[tn] = *(const f16x8*)&cBl[swz(rowb, q)];
        }
        __builtin_amdgcn_s_setprio(1);
#pragma unroll
        for (int tm = 0; tm < TMW; ++tm) {
            const int row = wm * (16 * TMW) + tm * 16 + l15;
            const f16x8 aH = *(const f16x8*)&cAh[swz(row, q)];
            const f16x8 aL = *(const f16x8*)&cAl[swz(row, q)];
#pragma unroll
            for (int tn = 0; tn < 4; ++tn) {
                acc[tm][tn] = __builtin_amdgcn_mfma_f32_16x16x32_f16(aH, bH[tn], acc[tm][tn], 0, 0, 0);
                acc[tm][tn] = __builtin_amdgcn_mfma_f32_16x16x32_f16(aH, bL[tn], acc[tm][tn], 0, 0, 0);
                acc[tm][tn] = __builtin_amdgcn_mfma_f32_16x16x32_f16(aL, bH[tn], acc[tm][tn], 0, 0, 0);
            }
        }
        __builtin_amdgcn_s_setprio(0);
        if (kt + 1 < ksteps) writeB(nBh, nBl);       // split once, amortized
        __syncthreads();                             // drains DMA + ds_writes
    }
    float bv[4];
#pragma unroll
    for (int tn = 0; tn < 4; ++tn) bv[tn] = bias[bn * 128 + wn * 64 + tn * 16 + l15];
#pragma unroll
    for (int tm = 0; tm < TMW; ++tm) {
        const int m0 = bm * MROWS + wm * (16 * TMW) + tm * 16 + q * 4;
#pragma unroll
        for (int tn = 0; tn < 4; ++tn) {
            const int n = bn * 128 + wn * 64 + tn * 16 + l15;
#pragma unroll
            for (int r = 0; r < 4; ++r) {
                float o = acc[tm][tn][r] + bv[tn];
                if (gates) o *= gates[(long)(m0 + r) * N + n];  // fused gating
                C[(long)(m0 + r) * N + n] = o;
            }
        }
    }
}

// ---------------------------------------------------------------------------
// Dendrite GEMM + abs-max gating epilogue. dend[b,n] = ctx[b,:].seg[n,:],
// n = h*10+s, 20480 rows. Tile 256(b)x320(n) = 32 h-groups, 8 waves 2x4
// (wave 128x80 = 8x5). Round-6 dbuf pipeline, LDS 144 KB. Epilogue:
// acc -> LDS [64][320] x4 chunks, argmax_s |dend| (strict > = jnp.argmax),
// sigmoid.
// ---------------------------------------------------------------------------
__global__ __launch_bounds__(512, 2) void dend_gemm(const _Float16* __restrict__ AH,
                                                    const _Float16* __restrict__ AL,
                                                    const float* __restrict__ seg,
                                                    float* __restrict__ gates) {
    extern __shared__ __align__(16) char smem[];
    _Float16* sAh0 = (_Float16*)smem;                // 16 KB each
    _Float16* sAl0 = (_Float16*)(smem + 16384);
    _Float16* sAh1 = (_Float16*)(smem + 32768);
    _Float16* sAl1 = (_Float16*)(smem + 49152);
    _Float16* sBh0 = (_Float16*)(smem + 65536);      // 20 KB each (320x32)
    _Float16* sBl0 = (_Float16*)(smem + 86016);
    _Float16* sBh1 = (_Float16*)(smem + 106496);
    _Float16* sBl1 = (_Float16*)(smem + 126976);     // ends 147456
    float* Cred = (float*)smem;                      // [64][320] union, 80 KB
    const int tid = threadIdx.x;
    const int w = tid >> 6, lane = tid & 63;
    const int wm = w >> 2, wn = w & 3;               // 2 x 4 waves
    const int q = lane >> 4, l15 = lane & 15;
    const int bm = blockIdx.x, bn = blockIdx.y;
    const long brow0 = (long)bn * 320;
    f32x4 acc[8][5] = {};
    float4 pre[5];
    auto loadB = [&](int kt) {
#pragma unroll
        for (int j = 0; j < 5; ++j) {
            const int c = tid + j * 512;             // 2560 float4 chunks
            const int row = c >> 3, hc = c & 7;
            pre[j] = *(const float4*)(seg + (brow0 + row) * 1024L + (kt << 5) + (hc << 2));
        }
    };
    auto writeB = [&](_Float16* bh, _Float16* bl) {
#pragma unroll
        for (int j = 0; j < 5; ++j) {
            const int c = tid + j * 512;
            const int row = c >> 3, hc = c & 7;
            const float4 v = pre[j];
            f16x4 h, l;
            h.x = (_Float16)v.x; l.x = (_Float16)(v.x - (float)h.x);
            h.y = (_Float16)v.y; l.y = (_Float16)(v.y - (float)h.y);
            h.z = (_Float16)v.z; l.z = (_Float16)(v.z - (float)h.z);
            h.w = (_Float16)v.w; l.w = (_Float16)(v.w - (float)h.w);
            const int off = row * 32 + (((hc >> 1) ^ ((row >> 1) & 3)) << 3) + ((hc & 1) << 2);
            *(f16x4*)(bh + off) = h;
            *(f16x4*)(bl + off) = l;
        }
    };
    loadB(0);
    dma_plane<256>(AH, (long)bm * 256, 1024, 0, sAh0, tid);
    dma_plane<256>(AL, (long)bm * 256, 1024, 0, sAl0, tid);
    writeB(sBh0, sBl0);
    __syncthreads();
    for (int kt = 0; kt < 32; ++kt) {
        const bool odd = kt & 1;
        const _Float16 *cAh = odd ? sAh1 : sAh0, *cAl = odd ? sAl1 : sAl0;
        const _Float16 *cBh = odd ? sBh1 : sBh0, *cBl = odd ? sBl1 : sBl0;
        _Float16 *nAh = odd ? sAh0 : sAh1, *nAl = odd ? sAl0 : sAl1;
        _Float16 *nBh = odd ? sBh0 : sBh1, *nBl = odd ? sBl0 : sBl1;
        if (kt < 31) {
            loadB(kt + 1);
            dma_plane<256>(AH, (long)bm * 256, 1024, (kt + 1) << 5, nAh, tid);
            dma_plane<256>(AL, (long)bm * 256, 1024, (kt + 1) << 5, nAl, tid);
        }
        f16x8 bH[5], bL[5];
#pragma unroll
        for (int tn = 0; tn < 5; ++tn) {
            const int rowb = wn * 80 + tn * 16 + l15;
            bH[tn] = *(const f16x8*)&cBh[swz(rowb, q)];
            bL[tn] = *(const f16x8*)&cBl[swz(rowb, q)];
        }
        __builtin_amdgcn_s_setprio(1);
#pragma unroll
        for (int tm = 0; tm < 8; ++tm) {
            const int row = wm * 128 + tm * 16 + l15;
            const f16x8 aH = *(const f16x8*)&cAh[swz(row, q)];
            const f16x8 aL = *(const f16x8*)&cAl[swz(row, q)];
#pragma unroll
            for (int tn = 0; tn < 5; ++tn) {
                acc[tm][tn] = __builtin_amdgcn_mfma_f32_16x16x32_f16(aH, bH[tn], acc[tm][tn], 0, 0, 0);
                acc[tm][tn] = __builtin_amdgcn_mfma_f32_16x16x32_f16(aH, bL[tn], acc[tm][tn], 0, 0, 0);
                acc[tm][tn] = __builtin_amdgcn_mfma_f32_16x16x32_f16(aL, bH[tn], acc[tm][tn], 0, 0, 0);
            }
        }
        __builtin_amdgcn_s_setprio(0);
        if (kt < 31) writeB(nBh, nBl);
        __syncthreads();
    }
    // epilogue: four 64-row chunks through LDS [64][320]. Scan reads stride
    // 10 fp32 -> <=4-way aliasing, epilogue-only (negligible).
    // chunk c rows = bm*256 + c*64..+63 -> wave wm == c>>1, tm (c&1)*4..+3
    for (int c = 0; c < 4; ++c) {
        __syncthreads();
        if (wm == (c >> 1)) {
            const int tmb = (c & 1) * 4;
#pragma unroll
            for (int tt = 0; tt < 4; ++tt)
#pragma unroll
                for (int tn = 0; tn < 5; ++tn)
#pragma unroll
                    for (int r = 0; r < 4; ++r)
                        Cred[(tt * 16 + q * 4 + r) * 320 + wn * 80 + tn * 16 + l15] =
                            acc[tmb + tt][tn][r];
        }
        __syncthreads();
        for (int p = tid; p < 2048; p += 512) {
            const int bb = p >> 5, hh = p & 31;
            const float* d = &Cred[bb * 320 + hh * 10];
            float best = d[0], ba = fabsf(d[0]);
#pragma unroll
            for (int s = 1; s < 10; ++s) {
                const float v = d[s], a = fabsf(v);
                if (a > ba) { ba = a; best = v; }    // strict >: first occurrence
            }
            const float gate = 1.f / (1.f + expf(-best));
            const int bg = bm * 256 + c * 64 + bb;
            const int h = bn * 32 + hh;
            gates[(long)bg * 2048 + h] = gate;
        }
    }
}

// ---------------------------------------------------------------------------
// KWinners on pre-gated v: exact 102nd-largest via radix select on
// order-preserving uint keys; keep where key >= kth (jnp `x >= kth` ties);
// emit h as f16 hi/lo planes (feeds next GEMM's A-DMA path).
// ---------------------------------------------------------------------------
__global__ __launch_bounds__(256) void kwinners_kernel(const float* __restrict__ vin,
                                                       _Float16* __restrict__ hH,
                                                       _Float16* __restrict__ hL) {
    __shared__ unsigned hist[256];
    __shared__ unsigned scan[257];
    __shared__ int sb, srank;
    const int tid = threadIdx.x;
    const long base = (long)blockIdx.x * 2048;
    float v[8];
    unsigned u[8];
#pragma unroll
    for (int j = 0; j < 8; ++j) {
        const int i = j * 256 + tid;
        const float val = vin[base + i];
        v[j] = val;
        const unsigned b = __float_as_uint(val);
        u[j] = b ^ (unsigned)((((int)b) >> 31) | 0x80000000);  // monotone map
    }
    unsigned prefix = 0, pmask = 0;
    int rank = 102;
    for (int round = 0; round < 4; ++round) {
        const int shift = 24 - (round << 3);
        hist[tid] = 0;
        if (tid == 0) scan[256] = 0;
        __syncthreads();
#pragma unroll
        for (int j = 0; j < 8; ++j)
            if ((u[j] & pmask) == prefix) atomicAdd(&hist[(u[j] >> shift) & 255], 1u);
        __syncthreads();
        scan[tid] = hist[tid];
        __syncthreads();
        for (int off = 1; off < 256; off <<= 1) {  // inclusive suffix sum
            const unsigned t = scan[tid] + ((tid + off < 256) ? scan[tid + off] : 0u);
            __syncthreads();
            scan[tid] = t;
            __syncthreads();
        }
        if (scan[tid] >= (unsigned)rank && scan[tid + 1] < (unsigned)rank) {
            sb = tid;
            srank = rank - (int)scan[tid + 1];
        }
        __syncthreads();
        prefix |= ((unsigned)sb) << shift;
        pmask |= 255u << shift;
        rank = srank;
        __syncthreads();
    }
#pragma unroll
    for (int j = 0; j < 8; ++j) {
        const int i = j * 256 + tid;
        const float hv = (u[j] >= prefix) ? v[j] : 0.f;
        const _Float16 hi = (_Float16)hv;
        hH[base + i] = hi;
        hL[base + i] = (_Float16)(hv - (float)hi);
    }
}

// ---------------------------------------------------------------------------
extern "C" void kernel_launch(void* const* d_in, const int* in_sizes, int n_in,
                              void* d_out, int out_size, void* d_ws, size_t ws_size,
                              hipStream_t stream) {
    const float* x    = (const float*)d_in[0];
    const float* ctx  = (const float*)d_in[1];
    const float* w1   = (const float*)d_in[2];
    const float* b1   = (const float*)d_in[3];
    const float* seg1 = (const float*)d_in[4];
    const float* w2   = (const float*)d_in[5];
    const float* b2   = (const float*)d_in[6];
    const float* seg2 = (const float*)d_in[7];
    const float* wo   = (const float*)d_in[8];
    const float* bo   = (const float*)d_in[9];

    // 96 MB workspace, time-multiplexed (gate fused into gemm frees 32 MB):
    //  [0,32):  gates1 -> h planes (hH@0, hL@16) after gates1 dead
    //  [32,64): v1 -> gates2 after v1 dead
    //  [64,96): ctxH@64 ctxL@72 xH@80 xL@88 -> v2 after ctx/x dead
    char* base = (char*)d_ws;
    float*    gates1 = (float*)base;
    _Float16* hH     = (_Float16*)base;
    _Float16* hL     = (_Float16*)(base + (16L << 20));
    float*    v1     = (float*)(base + (32L << 20));
    float*    gates2 = (float*)(base + (32L << 20));
    _Float16* ctxH   = (_Float16*)(base + (64L << 20));
    _Float16* ctxL   = (_Float16*)(base + (72L << 20));
    _Float16* xH     = (_Float16*)(base + (80L << 20));
    _Float16* xL     = (_Float16*)(base + (88L << 20));
    float*    v2     = (float*)(base + (64L << 20));
    (void)ws_size;

    hipFuncSetAttribute((const void*)dend_gemm,
                        hipFuncAttributeMaxDynamicSharedMemorySize, 147456);
    hipFuncSetAttribute((const void*)&gemm_f16p<4>,
                        hipFuncAttributeMaxDynamicSharedMemorySize, 98304);
    hipFuncSetAttribute((const void*)&gemm_f16p<2>,
                        hipFuncAttributeMaxDynamicSharedMemorySize, 65536);

    const int n4_ctx = (4096 * 1024) / 4;  // 1M float4 -> 4096 blocks

    // layer 1
    split_kernel<<<dim3(4096), dim3(256), 0, stream>>>(ctx, ctxH, ctxL, n4_ctx);
    split_kernel<<<dim3(4096), dim3(256), 0, stream>>>(x, xH, xL, n4_ctx);
    dend_gemm<<<dim3(16, 64), dim3(512), 147456, stream>>>(ctxH, ctxL, seg1, gates1);
    gemm_f16p<4><<<dim3(16, 16), dim3(512), 98304, stream>>>(xH, xL, w1, b1, gates1,
                                                             v1, 2048, 1024);
    kwinners_kernel<<<dim3(4096), dim3(256), 0, stream>>>(v1, hH, hL);
    // layer 2 (ctx planes persist — no re-split needed)
    dend_gemm<<<dim3(16, 64), dim3(512), 147456, stream>>>(ctxH, ctxL, seg2, gates2);
    gemm_f16p<4><<<dim3(16, 16), dim3(512), 98304, stream>>>(hH, hL, w2, b2, gates2,
                                                             v2, 2048, 2048);
    kwinners_kernel<<<dim3(4096), dim3(256), 0, stream>>>(v2, hH, hL);
    // output layer (no gating); 128-row tile -> grid (32,8) = 256 blocks,
    // full CU coverage (was 128 blocks = half the GPU idle)
    gemm_f16p<2><<<dim3(32, 8), dim3(512), 65536, stream>>>(hH, hL, wo, bo, nullptr,
                                                            (float*)d_out, 1024, 2048);
}